// Round 5
// 15450.488 us; speedup vs baseline: 1.0915x; 1.0915x over previous
//
#include <hip/hip_runtime.h>
#include <stdint.h>

// Problem dims
#define Bb 128
#define Tt 512
#define Hh 1024
#define Ss 128
#define Kk 64
#define HID 512
#define G3 3072
#define Dd 1152
#define KC 256     // K-chunk per LDS stage
#define LSTRA 264  // LDS stride (bf16) for KC=256 tiles: 528B/row -> 2-way conflicts only
#define LSTRS 72   // LDS stride for 64-wide tiles (state, Mt)

typedef short bf16x8 __attribute__((ext_vector_type(8)));
typedef float f32x4 __attribute__((ext_vector_type(4)));
typedef unsigned int u32x4v __attribute__((ext_vector_type(4)));
#define MFMA16 __builtin_amdgcn_mfma_f32_16x16x32_bf16

// ctrl counters, each padded to its own 128B line:
// CTR(1) gi_x done (64/step)  CTR(2) x-convert done (64/step)
// CTR(3) a=tanh(hW1) done (64/step)  CTR(4) logits+softmax done (8/step)
// CTR(5) h done (128/step)
#define CTR(i) (ctrl + (i) * 32)

__device__ __forceinline__ unsigned short f2bf(float f) {
  union { float f; unsigned u; } v; v.f = f;
  unsigned u = v.u;
  u += 0x7fffu + ((u >> 16) & 1u);
  return (unsigned short)(u >> 16);
}
__device__ __forceinline__ float sigm(float x) { return 1.f / (1.f + __expf(-x)); }
__device__ __forceinline__ float tanh_f(float x) {
  x = fminf(15.f, fmaxf(-15.f, x));
  float e = __expf(2.f * x);
  return (e - 1.f) / (e + 1.f);
}

// Coherent (L1+L2-bypassing) batched loads. Self-contained: loads + vmcnt(0)
// inside one asm block so compiler vmcnt bookkeeping elsewhere stays valid.
__device__ __forceinline__ void cload8(u32x4v o[8], const void* p, int sb) {
  const char* c = (const char*)p;
  asm volatile(
    "global_load_dwordx4 %0, %8, off sc0 sc1\n\t"
    "global_load_dwordx4 %1, %9, off sc0 sc1\n\t"
    "global_load_dwordx4 %2, %10, off sc0 sc1\n\t"
    "global_load_dwordx4 %3, %11, off sc0 sc1\n\t"
    "global_load_dwordx4 %4, %12, off sc0 sc1\n\t"
    "global_load_dwordx4 %5, %13, off sc0 sc1\n\t"
    "global_load_dwordx4 %6, %14, off sc0 sc1\n\t"
    "global_load_dwordx4 %7, %15, off sc0 sc1\n\t"
    "s_waitcnt vmcnt(0)"
    : "=&v"(o[0]), "=&v"(o[1]), "=&v"(o[2]), "=&v"(o[3]),
      "=&v"(o[4]), "=&v"(o[5]), "=&v"(o[6]), "=&v"(o[7])
    : "v"(c), "v"(c + sb), "v"(c + 2 * sb), "v"(c + 3 * sb),
      "v"(c + 4 * sb), "v"(c + 5 * sb), "v"(c + 6 * sb), "v"(c + 7 * sb)
    : "memory");
}
__device__ __forceinline__ void cload2(u32x4v o[2], const void* p, int sb) {
  const char* c = (const char*)p;
  asm volatile(
    "global_load_dwordx4 %0, %2, off sc0 sc1\n\t"
    "global_load_dwordx4 %1, %3, off sc0 sc1\n\t"
    "s_waitcnt vmcnt(0)"
    : "=&v"(o[0]), "=&v"(o[1])
    : "v"(c), "v"(c + sb)
    : "memory");
}
// 12 coherent scalar loads, ONE wait (widened round-0 cloadf4; same pattern).
__device__ __forceinline__ void cloadf12(float o[12],
    const float* a0, const float* a1, const float* a2, const float* a3,
    const float* a4, const float* a5, const float* a6, const float* a7,
    const float* a8, const float* a9, const float* a10, const float* a11) {
  asm volatile(
    "global_load_dword %0, %12, off sc0 sc1\n\t"
    "global_load_dword %1, %13, off sc0 sc1\n\t"
    "global_load_dword %2, %14, off sc0 sc1\n\t"
    "global_load_dword %3, %15, off sc0 sc1\n\t"
    "global_load_dword %4, %16, off sc0 sc1\n\t"
    "global_load_dword %5, %17, off sc0 sc1\n\t"
    "global_load_dword %6, %18, off sc0 sc1\n\t"
    "global_load_dword %7, %19, off sc0 sc1\n\t"
    "global_load_dword %8, %20, off sc0 sc1\n\t"
    "global_load_dword %9, %21, off sc0 sc1\n\t"
    "global_load_dword %10, %22, off sc0 sc1\n\t"
    "global_load_dword %11, %23, off sc0 sc1\n\t"
    "s_waitcnt vmcnt(0)"
    : "=&v"(o[0]), "=&v"(o[1]), "=&v"(o[2]), "=&v"(o[3]),
      "=&v"(o[4]), "=&v"(o[5]), "=&v"(o[6]), "=&v"(o[7]),
      "=&v"(o[8]), "=&v"(o[9]), "=&v"(o[10]), "=&v"(o[11])
    : "v"(a0), "v"(a1), "v"(a2), "v"(a3), "v"(a4), "v"(a5),
      "v"(a6), "v"(a7), "v"(a8), "v"(a9), "v"(a10), "v"(a11)
    : "memory");
}

// release: tid0 RMW; compiler emits buffer_wbl2 + waitcnt before the add,
// publishing this block's prior plain stores to the L3 coherence point.
__device__ __forceinline__ void rel_add(int* p) {
  __syncthreads();
  if (threadIdx.x == 0)
    __hip_atomic_fetch_add(p, 1, __ATOMIC_RELEASE, __HIP_MEMORY_SCOPE_AGENT);
}
// RELAXED poll — no cache maintenance ever. Data is read via cloadN (coherent).
__device__ __forceinline__ void wait_ge(int* p, int target) {
  __syncthreads();
  if (threadIdx.x == 0) {
    while (__hip_atomic_load(p, __ATOMIC_RELAXED, __HIP_MEMORY_SCOPE_AGENT) < target)
      __builtin_amdgcn_s_sleep(1);
  }
  __syncthreads();
}

// ---- prep kernels ----
__global__ void __launch_bounds__(256) prep_convert(const float* Whh, const float* Wih,
    const float* W1, const float* W2,
    unsigned short* WhhB, unsigned short* WXB, unsigned short* W1B, unsigned short* W2B) {
  const int n0 = G3 * Hh;
  const int n1 = n0 + G3 * Hh;
  const int n2 = n1 + HID * Hh;
  const int n3 = n2 + Kk * HID;
  for (int i = blockIdx.x * 256 + threadIdx.x; i < n3; i += gridDim.x * 256) {
    if (i < n0) WhhB[i] = f2bf(Whh[i]);
    else if (i < n1) { int j = i - n0; int n = j >> 10, k = j & 1023; WXB[j] = f2bf(Wih[n * Dd + k]); }
    else if (i < n2) { int j = i - n1; W1B[j] = f2bf(W1[j]); }
    else { int j = i - n2; W2B[j] = f2bf(W2[j]); }
  }
}
__global__ void __launch_bounds__(256) prep_mt(const float* Wih, const float* E, unsigned short* MtB) {
  int gid = blockIdx.x * 256 + threadIdx.x;
  if (gid >= G3 * Kk) return;
  int n = gid >> 6, kk = gid & 63;
  const float* wp = Wih + (size_t)n * Dd + Hh;
  const float* ep = E + kk * Ss;
  float s = 0.f;
  for (int t = 0; t < Ss; ++t) s += wp[t] * ep[t];
  MtB[n * Kk + kk] = f2bf(s);
}

// ---- A role: blocks 0..127 — recurrent gates + h update ----
// LDS: sA 64x264 | sBp 4x(48x264) persistent Whh | sMt 48x72 | sS 64x72 = 151296 B
__device__ void a_main(int bid, const float* init_state, const float* b_ih, const float* b_hh,
    const unsigned short* WhhB, const unsigned short* MtB,
    float* h32, unsigned short* hbf, const float* gix, const unsigned short* sbuf,
    int* ctrl, char* smem) {
  unsigned short* sA  = (unsigned short*)smem;
  unsigned short* sBp = (unsigned short*)(smem + 33792);
  unsigned short* sMt = (unsigned short*)(smem + 135168);
  unsigned short* sS  = (unsigned short*)(smem + 142080);
  const int tid = threadIdx.x;
  const int wv = tid >> 6, ln = tid & 63;
  const int mh = bid >> 6, jg = bid & 63;
  const int m0 = mh * 64, j0 = jg * 16;
  const int al = ln & 15, q = ln >> 4, koff = q * 8;
  const int j = j0 + al;
  const float bir = b_ih[j], biz = b_ih[Hh + j], bin_ = b_ih[2 * Hh + j];
  const float bhr = b_hh[j], bhz = b_hh[Hh + j], bhn = b_hh[2 * Hh + j];

  // one-time: Whh tiles (round-0 staging loop, hoisted; once per K-chunk)
  for (int kc = 0; kc < 4; ++kc) {
    const int k0 = kc * KC;
    unsigned short* sB = sBp + kc * (48 * LSTRA);
    int ch = tid;
#pragma unroll
    for (int u = 0; u < 6; ++u, ch += 256) {
      int r = ch >> 5, cc = (ch & 31) * 8;
      int g = r >> 4, rr = r & 15;
      *(u32x4v*)&sB[r * LSTRA + cc] = *(const u32x4v*)(WhhB + (g * Hh + j0 + rr) * Hh + k0 + cc);
    }
  }
  // one-time: Mt tile (round-0 staging loop, hoisted; stride LSTRS)
  for (int ch = tid; ch < 384; ch += 256) {
    int r = ch >> 3, cc = (ch & 7) * 8;
    int g = r >> 4, rr = r & 15;
    *(u32x4v*)&sMt[r * LSTRS + cc] = *(const u32x4v*)(MtB + (g * Hh + j0 + rr) * Kk + cc);
  }
  __syncthreads();

  for (int t = 0; t < Tt; ++t) {
    f32x4 accR = {0,0,0,0}, accZ = {0,0,0,0}, accNH = {0,0,0,0}, accNS = {0,0,0,0};

    if (t > 0) {
      wait_ge(CTR(5), 128 * t);   // all A finished t-1 (hbf[(t-1)&1] complete)
      const unsigned short* hb = hbf + ((t - 1) & 1) * (Bb * Hh);
      const int ra = tid >> 5, c8 = (tid & 31) * 8;
      for (int kc = 0; kc < 4; ++kc) {
        const int k0 = kc * KC;
        const unsigned short* sB = sBp + kc * (48 * LSTRA);
        __syncthreads();
        {
          u32x4v tmp[8];                                 // A: 64 rows x 256 k, coherent
          cload8(tmp, hb + (m0 + ra) * Hh + k0 + c8, 8 * Hh * 2);
#pragma unroll
          for (int u = 0; u < 8; ++u)
            *(u32x4v*)&sA[(ra + 8 * u) * LSTRA + c8] = tmp[u];
        }
        __syncthreads();
#pragma unroll
        for (int ks = 0; ks < 8; ++ks) {
          bf16x8 af  = *(bf16x8*)&sA[(wv * 16 + al) * LSTRA + ks * 32 + koff];
          bf16x8 b0  = *(bf16x8*)&sB[(al) * LSTRA + ks * 32 + koff];
          bf16x8 b1v = *(bf16x8*)&sB[(16 + al) * LSTRA + ks * 32 + koff];
          bf16x8 b2v = *(bf16x8*)&sB[(32 + al) * LSTRA + ks * 32 + koff];
          accR  = MFMA16(af, b0,  accR, 0, 0, 0);
          accZ  = MFMA16(af, b1v, accZ, 0, 0, 0);
          accNH = MFMA16(af, b2v, accNH, 0, 0, 0);
        }
      }
    }

    // gi_x_t prefetch: one batched issue + single wait
    wait_ge(CTR(1), 64 * (t + 1));
    float gx[12];
    {
      const float* gp = gix + (t & 1) * (Bb * G3) + (size_t)(m0 + wv * 16 + q * 4) * G3 + j;
      cloadf12(gx,
        gp,          gp + Hh,          gp + 2 * Hh,
        gp + G3,     gp + G3 + Hh,     gp + G3 + 2 * Hh,
        gp + 2 * G3, gp + 2 * G3 + Hh, gp + 2 * G3 + 2 * Hh,
        gp + 3 * G3, gp + 3 * G3 + Hh, gp + 3 * G3 + 2 * Hh);
    }

    // state probs for step t (round-0 structure; Mt already resident)
    __syncthreads();
    if (t > 0) {
      wait_ge(CTR(4), 8 * t);
      const unsigned short* sb = sbuf + ((t - 1) & 1) * (Bb * Kk);
      u32x4v tmp[2];                                     // 64 rows x 64 cols bf16, coherent
      cload2(tmp, sb + (m0 + (tid >> 3)) * Kk + (tid & 7) * 8, 32 * Kk * 2);
      *(u32x4v*)&sS[(tid >> 3) * LSTRS + (tid & 7) * 8] = tmp[0];
      *(u32x4v*)&sS[((tid >> 3) + 32) * LSTRS + (tid & 7) * 8] = tmp[1];
    } else {
      for (int e = tid; e < 4096; e += 256) {
        int r = e >> 6, k = e & 63;
        sS[r * LSTRS + k] = f2bf(init_state[(m0 + r) * Kk + k]);
      }
    }
    __syncthreads();
#pragma unroll
    for (int ks = 0; ks < 2; ++ks) {
      bf16x8 af  = *(bf16x8*)&sS[(wv * 16 + al) * LSTRS + ks * 32 + koff];
      bf16x8 b0  = *(bf16x8*)&sMt[(al) * LSTRS + ks * 32 + koff];
      bf16x8 b1v = *(bf16x8*)&sMt[(16 + al) * LSTRS + ks * 32 + koff];
      bf16x8 b2v = *(bf16x8*)&sMt[(32 + al) * LSTRS + ks * 32 + koff];
      accR  = MFMA16(af, b0,  accR, 0, 0, 0);
      accZ  = MFMA16(af, b1v, accZ, 0, 0, 0);
      accNS = MFMA16(af, b2v, accNS, 0, 0, 0);
    }

    const float* hp = h32 + ((t + 1) & 1) * (Bb * Hh);
    float* hc = h32 + (t & 1) * (Bb * Hh);
    unsigned short* hbc = hbf + (t & 1) * (Bb * Hh);
#pragma unroll
    for (int i = 0; i < 4; ++i) {
      const int m = m0 + wv * 16 + q * 4 + i;
      float gr  = accR[i] + gx[i * 3 + 0] + bir + bhr;
      float gz  = accZ[i] + gx[i * 3 + 1] + biz + bhz;
      float hn  = accNH[i] + bhn;
      float in_ = accNS[i] + gx[i * 3 + 2] + bin_;
      float r = sigm(gr), z = sigm(gz);
      float n = tanh_f(in_ + r * hn);
      float hprev = (t > 0) ? hp[m * Hh + j] : 0.f;      // own block's prior write
      float hnew = (1.f - z) * n + z * hprev;
      hc[m * Hh + j] = hnew;
      hbc[m * Hh + j] = f2bf(hnew);
    }
    rel_add(CTR(5));
  }
}

// ---- X role: blocks 128..191 — gi_x = x_t @ W_ihx^T (1 step ahead), 48 cols each ----
// (round-0 verbatim; WX tile does not fit LDS alongside the 128-row A tile)
__device__ void x_main(int xg, const float* ctx, unsigned short* xbf,
    const unsigned short* WXB, float* gix, int* ctrl,
    unsigned short* sA, unsigned short* sB) {
  const int tid = threadIdx.x;
  const int wv = tid >> 6, ln = tid & 63;
  const int al = ln & 15, q = ln >> 4, koff = q * 8;
  const int c0 = xg * 48;

  for (int tt = 0; tt < Tt; ++tt) {
    if (tt >= 2) wait_ge(CTR(1), 64 * (tt - 1));   // WAR: xbf[tt&1] readers done
    unsigned short* xb = xbf + (tt & 1) * (Bb * Hh);
    {
      int i4beg = xg * 512 + tid;
#pragma unroll
      for (int u = 0; u < 2; ++u) {
        int e = (i4beg + u * 256) * 4;
        int m = e >> 10, hh = e & 1023;
        const float4 v = *(const float4*)(ctx + (size_t)m * (Tt * Hh) + (size_t)tt * Hh + hh);
        ushort4 o;
        o.x = f2bf(v.x); o.y = f2bf(v.y); o.z = f2bf(v.z); o.w = f2bf(v.w);
        *(ushort4*)(xb + e) = o;
      }
    }
    rel_add(CTR(2));
    wait_ge(CTR(2), 64 * (tt + 1));

    f32x4 a00 = {0,0,0,0}, a01 = {0,0,0,0}, a02 = {0,0,0,0};
    f32x4 a10 = {0,0,0,0}, a11 = {0,0,0,0}, a12 = {0,0,0,0};
    const int ra = tid >> 5, c8 = (tid & 31) * 8;
    for (int kc = 0; kc < 4; ++kc) {
      const int k0 = kc * KC;
      __syncthreads();
      {
        u32x4v tmp[8];                                   // A: rows 0..63, coherent
        cload8(tmp, xb + ra * Hh + k0 + c8, 8 * Hh * 2);
#pragma unroll
        for (int u = 0; u < 8; ++u)
          *(u32x4v*)&sA[(ra + 8 * u) * LSTRA + c8] = tmp[u];
        u32x4v tmp2[8];                                  // A: rows 64..127
        cload8(tmp2, xb + (64 + ra) * Hh + k0 + c8, 8 * Hh * 2);
#pragma unroll
        for (int u = 0; u < 8; ++u)
          *(u32x4v*)&sA[(64 + ra + 8 * u) * LSTRA + c8] = tmp2[u];
      }
      {
        int ch = tid;
#pragma unroll
        for (int u = 0; u < 6; ++u, ch += 256) {         // B: 48 rows x 256 k, L2
          int r = ch >> 5, cc = (ch & 31) * 8;
          *(u32x4v*)&sB[r * LSTRA + cc] = *(const u32x4v*)(WXB + (c0 + r) * Hh + k0 + cc);
        }
      }
      __syncthreads();
#pragma unroll
      for (int ks = 0; ks < 8; ++ks) {
        bf16x8 a0  = *(bf16x8*)&sA[(wv * 32 + al) * LSTRA + ks * 32 + koff];
        bf16x8 a1  = *(bf16x8*)&sA[(wv * 32 + 16 + al) * LSTRA + ks * 32 + koff];
        bf16x8 b0  = *(bf16x8*)&sB[al * LSTRA + ks * 32 + koff];
        bf16x8 b1v = *(bf16x8*)&sB[(16 + al) * LSTRA + ks * 32 + koff];
        bf16x8 b2v = *(bf16x8*)&sB[(32 + al) * LSTRA + ks * 32 + koff];
        a00 = MFMA16(a0, b0,  a00, 0, 0, 0);
        a01 = MFMA16(a0, b1v, a01, 0, 0, 0);
        a02 = MFMA16(a0, b2v, a02, 0, 0, 0);
        a10 = MFMA16(a1, b0,  a10, 0, 0, 0);
        a11 = MFMA16(a1, b1v, a11, 0, 0, 0);
        a12 = MFMA16(a1, b2v, a12, 0, 0, 0);
      }
    }
    if (tt >= 2) wait_ge(CTR(5), 128 * (tt - 1));  // WAR: gix[tt&1] consumed by A(tt-2)
    float* go = gix + (tt & 1) * (Bb * G3);
#pragma unroll
    for (int i = 0; i < 4; ++i) {
      int mb = wv * 32 + q * 4 + i;
      go[mb * G3 + c0 + al] = a00[i];
      go[mb * G3 + c0 + 16 + al] = a01[i];
      go[mb * G3 + c0 + 32 + al] = a02[i];
      go[(mb + 16) * G3 + c0 + al] = a10[i];
      go[(mb + 16) * G3 + c0 + 16 + al] = a11[i];
      go[(mb + 16) * G3 + c0 + 32 + al] = a12[i];
    }
    rel_add(CTR(1));
  }
}

// ---- AL role: blocks 192..255 — a = tanh(hW1+b1); first 8 also logits+softmax ----
// LDS: sA 64x264 | sW1 4x(16x264) | sW2 2x(64x264) | softmax scratch = 139584 B
__device__ void al_main(int ag, const unsigned short* hbf,
    const unsigned short* W1B, const unsigned short* W2B, const float* b1, const float* b2,
    unsigned short* abf, unsigned short* sbuf, float* dout, int* ctrl, char* smem) {
  unsigned short* sA  = (unsigned short*)smem;
  unsigned short* sW1 = (unsigned short*)(smem + 33792);
  unsigned short* sW2 = (unsigned short*)(smem + 67584);
  float* sE   = (float*)(smem + 135168);     // 16 x 68 fp32 softmax scratch
  float* sInv = sE + 16 * 68;
  const int tid = threadIdx.x;
  const int wv = tid >> 6, ln = tid & 63;
  const int al = ln & 15, q = ln >> 4, koff = q * 8;
  const int c0 = (ag >> 1) * 16;     // 16 a-cols
  const int rh = (ag & 1) * 64;      // row half
  const float b1v = b1[c0 + al];
  const float b2v = b2[wv * 16 + al];

  // one-time: W1 tiles (round-0 staging loop, hoisted)
  for (int kc = 0; kc < 4; ++kc) {
    const int k0 = kc * KC;
    unsigned short* sB = sW1 + kc * (16 * LSTRA);
    int ch = tid;
#pragma unroll
    for (int u = 0; u < 2; ++u, ch += 256) {
      int r = ch >> 5, cc = (ch & 31) * 8;
      *(u32x4v*)&sB[r * LSTRA + cc] = *(const u32x4v*)(W1B + (c0 + r) * Hh + k0 + cc);
    }
  }
  // one-time: W2 tiles (only logits blocks read them)
  if (ag < 8) {
    for (int kc = 0; kc < 2; ++kc) {
      const int k0 = kc * KC;
      unsigned short* sB = sW2 + kc * (64 * LSTRA);
      int ch = tid;
#pragma unroll
      for (int u = 0; u < 8; ++u, ch += 256) {
        int r = ch >> 5, cc = (ch & 31) * 8;
        *(u32x4v*)&sB[r * LSTRA + cc] = *(const u32x4v*)(W2B + r * HID + k0 + cc);
      }
    }
  }
  __syncthreads();

  for (int s = 0; s < Tt; ++s) {
    wait_ge(CTR(5), 128 * (s + 1));            // h_s complete
    if (s >= 2) wait_ge(CTR(4), 8 * (s - 1));  // WAR: abf[s&1] readers done
    const unsigned short* hb = hbf + (s & 1) * (Bb * Hh);
    unsigned short* ab = abf + (s & 1) * (Bb * HID);

    f32x4 aa = {0,0,0,0};
    const int ra = tid >> 5, c8 = (tid & 31) * 8;
    for (int kc = 0; kc < 4; ++kc) {
      const int k0 = kc * KC;
      const unsigned short* sB = sW1 + kc * (16 * LSTRA);
      __syncthreads();
      {
        u32x4v tmp[8];                                   // A: 64 rows x 256 k, coherent
        cload8(tmp, hb + (rh + ra) * Hh + k0 + c8, 8 * Hh * 2);
#pragma unroll
        for (int u = 0; u < 8; ++u)
          *(u32x4v*)&sA[(ra + 8 * u) * LSTRA + c8] = tmp[u];
      }
      __syncthreads();
#pragma unroll
      for (int ks = 0; ks < 8; ++ks) {
        bf16x8 a0 = *(bf16x8*)&sA[(wv * 16 + al) * LSTRA + ks * 32 + koff];
        bf16x8 b0 = *(bf16x8*)&sB[al * LSTRA + ks * 32 + koff];
        aa = MFMA16(a0, b0, aa, 0, 0, 0);
      }
    }
#pragma unroll
    for (int i = 0; i < 4; ++i) {
      int mb = rh + wv * 16 + q * 4 + i;
      ab[mb * HID + c0 + al] = f2bf(tanh_f(aa[i] + b1v));
    }
    rel_add(CTR(3));

    if (ag < 8) {
      wait_ge(CTR(3), 64 * (s + 1));
      const int r0 = ag * 16;
      f32x4 lg = {0,0,0,0};
      for (int kc = 0; kc < 2; ++kc) {
        const int k0 = kc * KC;
        const unsigned short* sB = sW2 + kc * (64 * LSTRA);
        __syncthreads();
        {
          u32x4v tmp[2];                                 // A: 16 rows x 256 k, coherent
          cload2(tmp, ab + (r0 + ra) * HID + k0 + c8, 8 * HID * 2);
          *(u32x4v*)&sA[ra * LSTRA + c8] = tmp[0];
          *(u32x4v*)&sA[(ra + 8) * LSTRA + c8] = tmp[1];
        }
        __syncthreads();
#pragma unroll
        for (int ks = 0; ks < 8; ++ks) {
          bf16x8 af  = *(bf16x8*)&sA[al * LSTRA + ks * 32 + koff];
          bf16x8 bf_ = *(bf16x8*)&sB[(wv * 16 + al) * LSTRA + ks * 32 + koff];
          lg = MFMA16(af, bf_, lg, 0, 0, 0);
        }
      }
      float vraw[4], ev[4];
#pragma unroll
      for (int i = 0; i < 4; ++i) {
        float v = lg[i] + b2v;
        vraw[i] = v;
        float c = fminf(10.f, fmaxf(-10.f, v));
        ev[i] = __expf(c);
        sE[(q * 4 + i) * 68 + (wv * 16 + al)] = ev[i];
      }
      __syncthreads();
      if (tid < 16) {
        const float* row = &sE[tid * 68];
        float sm = 0.f;
        for (int k = 0; k < 64; ++k) sm += row[k];
        sInv[tid] = 1.f / sm;
      }
      __syncthreads();
      const int col = wv * 16 + al;
      unsigned short* sb = sbuf + (s & 1) * (Bb * Kk);
#pragma unroll
      for (int i = 0; i < 4; ++i) {
        int row16 = q * 4 + i;
        int grow = r0 + row16;
        dout[grow * (Tt * Kk) + s * Kk + col] = vraw[i];
        sb[grow * Kk + col] = f2bf(ev[i] * sInv[row16]);
      }
      rel_add(CTR(4));
    }
  }
}

__global__ void __launch_bounds__(256, 1)
seqkern(const float* ctx, const float* init_state, const float* b_ih, const float* b_hh,
        const float* b1, const float* b2, float* dout,
        const unsigned short* WhhB, const unsigned short* WXB, const unsigned short* W1B,
        const unsigned short* W2B, const unsigned short* MtB,
        float* h32, unsigned short* hbf, float* gix, unsigned short* xbf,
        unsigned short* abf, unsigned short* sbuf, int* ctrl) {
  extern __shared__ char smem[];   // A: 151296 B, AL: 139584 B, X: 101376 B
  const int bid = blockIdx.x;
  if (bid < 128)
    a_main(bid, init_state, b_ih, b_hh, WhhB, MtB, h32, hbf, gix, sbuf, ctrl, smem);
  else if (bid < 192)
    x_main(bid - 128, ctx, xbf, WXB, gix, ctrl,
           (unsigned short*)smem, (unsigned short*)(smem + 67584));
  else
    al_main(bid - 192, hbf, W1B, W2B, b1, b2, abf, sbuf, dout, ctrl, smem);
}

extern "C" void kernel_launch(void* const* d_in, const int* in_sizes, int n_in,
                              void* d_out, int out_size, void* d_ws, size_t ws_size,
                              hipStream_t stream) {
  const float* ctx        = (const float*)d_in[0];
  const float* init_state = (const float*)d_in[1];
  const float* E          = (const float*)d_in[2];
  const float* Wih        = (const float*)d_in[3];
  const float* Whh        = (const float*)d_in[4];
  const float* b_ih       = (const float*)d_in[5];
  const float* b_hh       = (const float*)d_in[6];
  const float* W1         = (const float*)d_in[7];
  const float* b1         = (const float*)d_in[8];
  const float* W2         = (const float*)d_in[9];
  const float* b2         = (const float*)d_in[10];
  float* out = (float*)d_out;
  (void)in_sizes; (void)n_in; (void)out_size; (void)ws_size;

  char* ws = (char*)d_ws;
  size_t off = 0;
  auto take = [&](size_t sz) { char* p = ws + off; off += (sz + 255) & ~(size_t)255; return p; };
  int* ctrl             = (int*)take(1024);
  unsigned short* WhhB  = (unsigned short*)take((size_t)G3 * Hh * 2);
  unsigned short* WXB   = (unsigned short*)take((size_t)G3 * Hh * 2);
  unsigned short* W1B   = (unsigned short*)take((size_t)HID * Hh * 2);
  unsigned short* W2B   = (unsigned short*)take((size_t)Kk * HID * 2);
  unsigned short* MtB   = (unsigned short*)take((size_t)G3 * Kk * 2);
  float* h32            = (float*)take((size_t)2 * Bb * Hh * 4);
  unsigned short* hbf   = (unsigned short*)take((size_t)2 * Bb * Hh * 2);
  float* gix            = (float*)take((size_t)2 * Bb * G3 * 4);
  unsigned short* xbf   = (unsigned short*)take((size_t)2 * Bb * Hh * 2);
  unsigned short* abf   = (unsigned short*)take((size_t)2 * Bb * HID * 2);
  unsigned short* sbuf  = (unsigned short*)take((size_t)2 * Bb * Kk * 2);

  hipMemsetAsync(ctrl, 0, 1024, stream);
  hipLaunchKernelGGL(prep_convert, dim3(2048), dim3(256), 0, stream,
                     Whh, Wih, W1, W2, WhhB, WXB, W1B, W2B);
  hipLaunchKernelGGL(prep_mt, dim3(768), dim3(256), 0, stream, Wih, E, MtB);

  static int smem_set = 0;
  if (!smem_set) {
    hipFuncSetAttribute((const void*)seqkern,
                        hipFuncAttributeMaxDynamicSharedMemorySize, 151296);
    smem_set = 1;
  }
  void* args[] = {(void*)&ctx, (void*)&init_state, (void*)&b_ih, (void*)&b_hh,
                  (void*)&b1, (void*)&b2, (void*)&out,
                  (void*)&WhhB, (void*)&WXB, (void*)&W1B, (void*)&W2B, (void*)&MtB,
                  (void*)&h32, (void*)&hbf, (void*)&gix, (void*)&xbf,
                  (void*)&abf, (void*)&sbuf, (void*)&ctrl};
  hipLaunchCooperativeKernel((const void*)seqkern, dim3(256), dim3(256), args, 151296, stream);
}